// Round 1
// baseline (896.177 us; speedup 1.0000x reference)
//
#include <hip/hip_runtime.h>

#define N_NODES 50000
#define N_EDGES 600000
#define N_REL 8
#define D 128
#define D2 256

// out[n][c] = sum_i X[n][i] * W[i][c] (+ bias[c])
// 16 nodes per block, 256 threads: thread = (column c in 0..127, half h in 0..1)
// each thread accumulates 8 nodes for its column.
template<bool BIAS>
__global__ void node_gemm128(const float* __restrict__ X, const float* __restrict__ W,
                             const float* __restrict__ bias, float* __restrict__ out) {
    __shared__ float xs[16][D];
    const int t = threadIdx.x;
    const int n0 = blockIdx.x * 16;
#pragma unroll
    for (int k = 0; k < 8; ++k) {
        int idx = t + k * 256;          // 0..2047
        int nl = idx >> 7, i = idx & 127;
        xs[nl][i] = X[(n0 + nl) * D + i];
    }
    __syncthreads();
    const int c = t & 127, h = t >> 7;
    float acc[8];
#pragma unroll
    for (int j = 0; j < 8; ++j) acc[j] = 0.f;
    for (int i = 0; i < D; ++i) {
        float w = W[i * D + c];
#pragma unroll
        for (int j = 0; j < 8; ++j) acc[j] += xs[h * 8 + j][i] * w;
    }
    float b = BIAS ? bias[c] : 0.f;
#pragma unroll
    for (int j = 0; j < 8; ++j)
        out[(n0 + h * 8 + j) * D + c] = acc[j] + b;
}

// For edges with etype==rel: agg[dst] += xwr[src]  (128 threads = one column each)
__global__ void edge_scatter(const int* __restrict__ src, const int* __restrict__ dst,
                             const int* __restrict__ etype, const float* __restrict__ xwr,
                             float* __restrict__ agg, int rel) {
    const int t = threadIdx.x;          // 0..127
    const int e0 = blockIdx.x * 64;
    for (int e = 0; e < 64; ++e) {
        int eg = e0 + e;
        if (eg >= N_EDGES) break;
        if (etype[eg] != rel) continue;  // uniform branch per block
        int s = src[eg], d = dst[eg];
        atomicAdd(&agg[d * D + t], xwr[s * D + t]);
    }
}

// h = relu(concat(x, mid) @ W1 + b1); out = h @ W2 + b2
// 16 nodes per block, 256 threads.
__global__ void mlp_fused(const float* __restrict__ x, const float* __restrict__ mid,
                          const float* __restrict__ W1, const float* __restrict__ b1,
                          const float* __restrict__ W2, const float* __restrict__ b2,
                          float* __restrict__ out) {
    __shared__ float hrow[16][D2];
    __shared__ float h1s[16][D2];
    const int t = threadIdx.x;
    const int n0 = blockIdx.x * 16;
#pragma unroll
    for (int k = 0; k < 16; ++k) {
        int idx = t + k * 256;          // 0..4095
        int nl = idx >> 8, i = idx & 255;
        int n = n0 + nl;
        hrow[nl][i] = (i < D) ? x[n * D + i] : mid[n * D + (i - D)];
    }
    __syncthreads();
    {   // layer 1: thread owns column t (0..255), 16 nodes
        float acc[16];
#pragma unroll
        for (int j = 0; j < 16; ++j) acc[j] = 0.f;
        for (int i = 0; i < D2; ++i) {
            float w = W1[i * D2 + t];
#pragma unroll
            for (int j = 0; j < 16; ++j) acc[j] += hrow[j][i] * w;
        }
        float b = b1[t];
#pragma unroll
        for (int j = 0; j < 16; ++j)
            h1s[j][t] = fmaxf(acc[j] + b, 0.f);
    }
    __syncthreads();
    {   // layer 2: thread = (column c in 0..127, half h), 8 nodes each
        const int c = t & 127, h = t >> 7;
        float acc[8];
#pragma unroll
        for (int j = 0; j < 8; ++j) acc[j] = 0.f;
        for (int i = 0; i < D2; ++i) {
            float w = W2[i * D + c];
#pragma unroll
            for (int j = 0; j < 8; ++j) acc[j] += h1s[h * 8 + j][i] * w;
        }
        float b = b2[c];
#pragma unroll
        for (int j = 0; j < 8; ++j)
            out[(n0 + h * 8 + j) * D + c] = acc[j] + b;
    }
}

extern "C" void kernel_launch(void* const* d_in, const int* in_sizes, int n_in,
                              void* d_out, int out_size, void* d_ws, size_t ws_size,
                              hipStream_t stream) {
    const float* x     = (const float*)d_in[0];
    const int*   src   = (const int*)  d_in[1];
    const int*   dst   = (const int*)  d_in[2];
    const int*   etype = (const int*)  d_in[3];
    const float* Wrel  = (const float*)d_in[4];
    const float* Wloop = (const float*)d_in[5];
    const float* brel  = (const float*)d_in[6];
    const float* W1    = (const float*)d_in[7];
    const float* b1    = (const float*)d_in[8];
    const float* W2    = (const float*)d_in[9];
    const float* b2    = (const float*)d_in[10];
    float* out = (float*)d_out;

    float* agg = (float*)d_ws;                 // [N_NODES, D]   25.6 MB
    float* xwr = agg + (size_t)N_NODES * D;    // [N_NODES, D]   25.6 MB

    // 1) agg = x @ Wloop + brel  (self-loop, also initializes agg)
    node_gemm128<true><<<N_NODES / 16, 256, 0, stream>>>(x, Wloop, brel, agg);

    // 2) per relation: xwr = x @ Wrel[r]; agg[dst] += xwr[src] for etype==r
    for (int r = 0; r < N_REL; ++r) {
        node_gemm128<false><<<N_NODES / 16, 256, 0, stream>>>(x, Wrel + (size_t)r * D * D, nullptr, xwr);
        edge_scatter<<<N_EDGES / 64, 128, 0, stream>>>(src, dst, etype, xwr, agg, r);
    }

    // 3) out = relu(concat(x, agg) @ W1 + b1) @ W2 + b2
    mlp_fused<<<N_NODES / 16, 256, 0, stream>>>(x, agg, W1, b1, W2, b2, out);
}

// Round 2
// 779.366 us; speedup vs baseline: 1.1499x; 1.1499x over previous
//
#include <hip/hip_runtime.h>

#define N_NODES 50000
#define N_EDGES 600000
#define N_REL 8

typedef __attribute__((ext_vector_type(8))) short bf16x8;
typedef __attribute__((ext_vector_type(4))) float f32x4;

__device__ __forceinline__ ushort f2b(float f) {
    union { float f; unsigned u; } v; v.f = f;
    unsigned r = v.u + 0x7FFFu + ((v.u >> 16) & 1u);
    return (ushort)(r >> 16);
}
__device__ __forceinline__ float b2f(ushort s) {
    union { unsigned u; float f; } v; v.u = ((unsigned)s) << 16;
    return v.f;
}

// x (f32) -> bf16, 4 elems/thread
__global__ void conv_x(const float* __restrict__ x, ushort* __restrict__ xb) {
    int i = (blockIdx.x * 256 + threadIdx.x) * 4;
    float4 f = *(const float4*)(x + i);
    ushort4 o; o.x = f2b(f.x); o.y = f2b(f.y); o.z = f2b(f.z); o.w = f2b(f.w);
    *(ushort4*)(xb + i) = o;
}

// transpose+convert all weight matrices into wt (bf16, [C][K] row-major)
__global__ void transpose_wts(const float* __restrict__ Wloop, const float* __restrict__ Wrel,
                              const float* __restrict__ W1, const float* __restrict__ W2,
                              ushort* __restrict__ wt) {
    int y = blockIdx.y;
    const float* src; int K, C; size_t doff;
    if (y == 0)      { src = Wloop;                       K = 128; C = 128; doff = 0; }
    else if (y <= 8) { src = Wrel + (size_t)(y - 1) * 16384; K = 128; C = 128; doff = 16384 + (size_t)(y - 1) * 16384; }
    else if (y == 9) { src = W1;                          K = 256; C = 256; doff = 147456; }
    else             { src = W2;                          K = 256; C = 128; doff = 212992; }
    int total = K * C;
    for (int idx = blockIdx.x * 256 + threadIdx.x; idx < total; idx += gridDim.x * 256) {
        int c = idx / K, k = idx - c * K;
        wt[doff + idx] = f2b(src[k * C + c]);
    }
}

// out[r][c] = sum_k A[r][k] * Bt[c][k]  via mfma_f32_16x16x32_bf16
// block = 256 threads (4 waves), 64 rows/block, each wave: 16 rows x C cols.
// AMODE 0: A = bf16 [N][K].  AMODE 1 (K=256): k<128 from A (bf16 [N][128]), k>=128 from Amid (f32 [N][128]).
// OMODE 0: f32 out + bias.  OMODE 1: bf16 out, no bias, +blockIdx.y*N*C offset.  OMODE 2: bf16 relu(out+bias).
template<int K, int C, int AMODE, int OMODE>
__global__ __launch_bounds__(256) void mfma_gemm(
        const ushort* __restrict__ A, const float* __restrict__ Amid,
        const ushort* __restrict__ Bt, const float* __restrict__ bias,
        void* __restrict__ outv) {
    const int t = threadIdx.x;
    const int wave = t >> 6, lane = t & 63;
    const int lr = lane & 15, lg = lane >> 4;
    const int row0 = blockIdx.x * 64 + wave * 16;
    const ushort* Btb = Bt + (size_t)blockIdx.y * C * K;

    int arow = row0 + lr;
    if (arow >= N_NODES) arow = 0;

    bf16x8 af[K / 32];
#pragma unroll
    for (int kc = 0; kc < K / 32; ++kc) {
        if (AMODE == 0) {
            af[kc] = *(const bf16x8*)(A + (size_t)arow * K + kc * 32 + lg * 8);
        } else {
            if (kc < 4) {
                af[kc] = *(const bf16x8*)(A + (size_t)arow * 128 + kc * 32 + lg * 8);
            } else {
                const float* mp = Amid + (size_t)arow * 128 + (kc - 4) * 32 + lg * 8;
                f32x4 m0 = *(const f32x4*)mp;
                f32x4 m1 = *(const f32x4*)(mp + 4);
                union { bf16x8 v; ushort s[8]; } u;
                u.s[0] = f2b(m0[0]); u.s[1] = f2b(m0[1]); u.s[2] = f2b(m0[2]); u.s[3] = f2b(m0[3]);
                u.s[4] = f2b(m1[0]); u.s[5] = f2b(m1[1]); u.s[6] = f2b(m1[2]); u.s[7] = f2b(m1[3]);
                af[kc] = u.v;
            }
        }
    }

    f32x4 acc[C / 16];
#pragma unroll
    for (int nt = 0; nt < C / 16; ++nt) acc[nt] = (f32x4){0.f, 0.f, 0.f, 0.f};

#pragma unroll
    for (int kc = 0; kc < K / 32; ++kc) {
#pragma unroll
        for (int nt = 0; nt < C / 16; ++nt) {
            bf16x8 bf = *(const bf16x8*)(Btb + (size_t)(nt * 16 + lr) * K + kc * 32 + lg * 8);
            acc[nt] = __builtin_amdgcn_mfma_f32_16x16x32_bf16(af[kc], bf, acc[nt], 0, 0, 0);
        }
    }

#pragma unroll
    for (int nt = 0; nt < C / 16; ++nt) {
        const int col = nt * 16 + lr;
        float bv = (OMODE == 1) ? 0.f : bias[col];
#pragma unroll
        for (int j = 0; j < 4; ++j) {
            const int r = row0 + lg * 4 + j;
            if (r >= N_NODES) continue;
            float vv = acc[nt][j];
            if (OMODE == 0) {
                ((float*)outv)[(size_t)r * C + col] = vv + bv;
            } else if (OMODE == 1) {
                ((ushort*)outv)[((size_t)blockIdx.y * N_NODES + r) * C + col] = f2b(vv);
            } else {
                ((ushort*)outv)[(size_t)r * C + col] = f2b(fmaxf(vv + bv, 0.f));
            }
        }
    }
}

// one pass over all edges for relations [rel0, rel0+4): mid[dst] += xw[rel_local][src]
// 4 edges/block, 64 lanes/edge, lane handles 2 adjacent columns (one dword read).
__global__ __launch_bounds__(256) void edge_scatter2(
        const int* __restrict__ src, const int* __restrict__ dst,
        const int* __restrict__ et, const ushort* __restrict__ xw,
        float* __restrict__ mid, int rel0) {
    const int t = threadIdx.x;
    const int e = blockIdx.x * 4 + (t >> 6);
    const int lane = t & 63;
    const int r = et[e] - rel0;
    if ((unsigned)r >= 4u) return;
    const int s = src[e], d = dst[e];
    unsigned v = *(const unsigned*)(xw + ((size_t)r * N_NODES + s) * 128 + lane * 2);
    atomicAdd(&mid[(size_t)d * 128 + lane * 2],     b2f((ushort)(v & 0xffffu)));
    atomicAdd(&mid[(size_t)d * 128 + lane * 2 + 1], b2f((ushort)(v >> 16)));
}

extern "C" void kernel_launch(void* const* d_in, const int* in_sizes, int n_in,
                              void* d_out, int out_size, void* d_ws, size_t ws_size,
                              hipStream_t stream) {
    const float* x     = (const float*)d_in[0];
    const int*   src   = (const int*)  d_in[1];
    const int*   dst   = (const int*)  d_in[2];
    const int*   etype = (const int*)  d_in[3];
    const float* Wrel  = (const float*)d_in[4];
    const float* Wloop = (const float*)d_in[5];
    const float* brel  = (const float*)d_in[6];
    const float* W1    = (const float*)d_in[7];
    const float* b1    = (const float*)d_in[8];
    const float* W2    = (const float*)d_in[9];
    const float* b2    = (const float*)d_in[10];
    float* out = (float*)d_out;

    char* ws = (char*)d_ws;
    ushort* xbf = (ushort*)ws;                    // 12,800,000 B  x in bf16
    ushort* wt  = (ushort*)(ws + 12800000);       //    491,520 B  all weights bf16 transposed
    ushort* xw  = (ushort*)(ws + 13291520);       // 51,200,000 B  xw for 4 relations (reused as h)

    const ushort* wtl = wt;              // [128][128]
    const ushort* wtr = wt + 16384;      // [8][128][128]
    const ushort* w1t = wt + 147456;     // [256][256]
    const ushort* w2t = wt + 212992;     // [128][256]

    conv_x<<<6250, 256, 0, stream>>>(x, xbf);
    transpose_wts<<<dim3(64, 11), 256, 0, stream>>>(Wloop, Wrel, W1, W2, wt);

    // mid (= d_out, f32) = x @ Wloop + brel
    mfma_gemm<128, 128, 0, 0><<<dim3(782, 1), 256, 0, stream>>>(xbf, nullptr, wtl, brel, out);

    for (int g = 0; g < 2; ++g) {
        // xw[b] = x @ Wrel[g*4+b]  (bf16), b = 0..3
        mfma_gemm<128, 128, 0, 1><<<dim3(782, 4), 256, 0, stream>>>(
            xbf, nullptr, wtr + (size_t)g * 4 * 16384, nullptr, (void*)xw);
        // mid[dst] += xw[etype-g*4][src]
        edge_scatter2<<<N_EDGES / 4, 256, 0, stream>>>(src, dst, etype, xw, out, g * 4);
    }

    // h (bf16, in xw region) = relu(concat(x, mid) @ W1 + b1)
    mfma_gemm<256, 256, 1, 2><<<dim3(782, 1), 256, 0, stream>>>(xbf, out, w1t, b1, (void*)xw);
    // out = h @ W2 + b2
    mfma_gemm<256, 128, 0, 0><<<dim3(782, 1), 256, 0, stream>>>(xw, nullptr, w2t, b2, out);
}

// Round 4
// 460.582 us; speedup vs baseline: 1.9457x; 1.6921x over previous
//
#include <hip/hip_runtime.h>

#define N_NODES 50000
#define N_EDGES 600000
#define N_REL 8
#define NT_PAD 50176      // 196 * 256
#define N_TILES 196

typedef __attribute__((ext_vector_type(8))) short bf16x8;
typedef __attribute__((ext_vector_type(4))) float f32x4;

__device__ __forceinline__ ushort f2b(float f) {
    union { float f; unsigned u; } v; v.f = f;
    unsigned r = v.u + 0x7FFFu + ((v.u >> 16) & 1u);
    return (ushort)(r >> 16);
}
__device__ __forceinline__ float b2f(ushort s) {
    union { unsigned u; float f; } v; v.u = ((unsigned)s) << 16;
    return v.f;
}

// ---------------- weight transpose+convert ----------------

__global__ void transpose_wts(const float* __restrict__ Wloop, const float* __restrict__ Wrel,
                              const float* __restrict__ W1, const float* __restrict__ W2,
                              ushort* __restrict__ wt) {
    int y = blockIdx.y;
    const float* src; int K, C; size_t doff;
    if (y == 0)      { src = Wloop;                       K = 128; C = 128; doff = 0; }
    else if (y <= 8) { src = Wrel + (size_t)(y - 1) * 16384; K = 128; C = 128; doff = 16384 + (size_t)(y - 1) * 16384; }
    else if (y == 9) { src = W1;                          K = 256; C = 256; doff = 147456; }
    else             { src = W2;                          K = 256; C = 128; doff = 212992; }
    int total = K * C;
    for (int idx = blockIdx.x * 256 + threadIdx.x; idx < total; idx += gridDim.x * 256) {
        int c = idx / K, k = idx - c * K;
        wt[doff + idx] = f2b(src[k * C + c]);
    }
}

// ---------------- MFMA GEMM ----------------
// out[r][c] = sum_k A[r][k] * Bt[c][k]  via mfma_f32_16x16x32_bf16
// AMODE 0: A = f32 [N][128] (K=128), converted inline.
// AMODE 1: K=256, k<128 from A (f32 [N][128]), k>=128 from Amid (f32 [N][128]).
// AMODE 2: A = bf16 [N][K].
// OMODE 0: f32 out + bias.  OMODE 1: bf16 out, no bias, +blockIdx.y*N*C offset.  OMODE 2: bf16 relu(out+bias).
template<int K, int C, int AMODE, int OMODE>
__global__ __launch_bounds__(256) void mfma_gemm(
        const void* __restrict__ Av, const float* __restrict__ Amid,
        const ushort* __restrict__ Bt, const float* __restrict__ bias,
        void* __restrict__ outv) {
    const int t = threadIdx.x;
    const int wave = t >> 6, lane = t & 63;
    const int lr = lane & 15, lg = lane >> 4;
    const int row0 = blockIdx.x * 64 + wave * 16;
    const ushort* Btb = Bt + (size_t)blockIdx.y * C * K;

    int arow = row0 + lr;
    if (arow >= N_NODES) arow = 0;

    bf16x8 af[K / 32];
#pragma unroll
    for (int kc = 0; kc < K / 32; ++kc) {
        if (AMODE == 2) {
            af[kc] = *(const bf16x8*)((const ushort*)Av + (size_t)arow * K + kc * 32 + lg * 8);
        } else {
            const float* fp;
            if (AMODE == 0 || kc < 4)
                fp = (const float*)Av + (size_t)arow * 128 + kc * 32 + lg * 8;
            else
                fp = Amid + (size_t)arow * 128 + (kc - 4) * 32 + lg * 8;
            f32x4 m0 = *(const f32x4*)fp;
            f32x4 m1 = *(const f32x4*)(fp + 4);
            union { bf16x8 v; ushort s[8]; } u;
            u.s[0] = f2b(m0[0]); u.s[1] = f2b(m0[1]); u.s[2] = f2b(m0[2]); u.s[3] = f2b(m0[3]);
            u.s[4] = f2b(m1[0]); u.s[5] = f2b(m1[1]); u.s[6] = f2b(m1[2]); u.s[7] = f2b(m1[3]);
            af[kc] = u.v;
        }
    }

    f32x4 acc[C / 16];
#pragma unroll
    for (int nt = 0; nt < C / 16; ++nt) acc[nt] = (f32x4){0.f, 0.f, 0.f, 0.f};

#pragma unroll
    for (int kc = 0; kc < K / 32; ++kc) {
#pragma unroll
        for (int nt = 0; nt < C / 16; ++nt) {
            bf16x8 bf = *(const bf16x8*)(Btb + (size_t)(nt * 16 + lr) * K + kc * 32 + lg * 8);
            acc[nt] = __builtin_amdgcn_mfma_f32_16x16x32_bf16(af[kc], bf, acc[nt], 0, 0, 0);
        }
    }

#pragma unroll
    for (int nt = 0; nt < C / 16; ++nt) {
        const int col = nt * 16 + lr;
        float bv = (OMODE == 1) ? 0.f : bias[col];
#pragma unroll
        for (int j = 0; j < 4; ++j) {
            const int r = row0 + lg * 4 + j;
            if (r >= N_NODES) continue;
            float vv = acc[nt][j];
            if (OMODE == 0) {
                ((float*)outv)[(size_t)r * C + col] = vv + bv;
            } else if (OMODE == 1) {
                ((ushort*)outv)[((size_t)blockIdx.y * N_NODES + r) * C + col] = f2b(vv);
            } else {
                ((ushort*)outv)[(size_t)r * C + col] = f2b(fmaxf(vv + bv, 0.f));
            }
        }
    }
}

// ---------------- CSR build (counting sort by dst) ----------------

__global__ void zero_cnt(int* __restrict__ cnt) {
    int i = blockIdx.x * 256 + threadIdx.x;
    if (i < NT_PAD) cnt[i] = 0;
}

__global__ void hist_dst(const int* __restrict__ dst, int* __restrict__ cnt) {
    int e = blockIdx.x * 256 + threadIdx.x;
    if (e < N_EDGES) atomicAdd(&cnt[dst[e]], 1);
}

__global__ void scan_tiles(const int* __restrict__ cnt, int* __restrict__ tincl, int* __restrict__ bsum) {
    __shared__ int s[256];
    int i = blockIdx.x * 256 + threadIdx.x;
    int v = cnt[i];
    s[threadIdx.x] = v;
    __syncthreads();
    for (int off = 1; off < 256; off <<= 1) {
        int add = (threadIdx.x >= off) ? s[threadIdx.x - off] : 0;
        __syncthreads();
        s[threadIdx.x] += add;
        __syncthreads();
    }
    tincl[i] = s[threadIdx.x];
    if (threadIdx.x == 255) bsum[blockIdx.x] = s[255];
}

__global__ void scan_bsum(const int* __restrict__ bsum, int* __restrict__ bex) {
    __shared__ int s[256];
    int v = (threadIdx.x < N_TILES) ? bsum[threadIdx.x] : 0;
    s[threadIdx.x] = v;
    __syncthreads();
    for (int off = 1; off < 256; off <<= 1) {
        int add = (threadIdx.x >= off) ? s[threadIdx.x - off] : 0;
        __syncthreads();
        s[threadIdx.x] += add;
        __syncthreads();
    }
    if (threadIdx.x < N_TILES) bex[threadIdx.x] = s[threadIdx.x] - v;
}

__global__ void finalize_base(const int* __restrict__ cnt, const int* __restrict__ tincl,
                              const int* __restrict__ bex, int* __restrict__ base,
                              int* __restrict__ cursor) {
    int i = blockIdx.x * 256 + threadIdx.x;
    int b = tincl[i] - cnt[i] + bex[blockIdx.x];
    base[i] = b; cursor[i] = b;
}

__global__ void scatter_ids(const int* __restrict__ src, const int* __restrict__ dst,
                            const int* __restrict__ et, int* __restrict__ cursor,
                            unsigned* __restrict__ sorted) {
    int e = blockIdx.x * 256 + threadIdx.x;
    if (e >= N_EDGES) return;
    int pos = atomicAdd(&cursor[dst[e]], 1);
    sorted[pos] = ((unsigned)src[e] << 3) | (unsigned)et[e];
}

// ---------------- gather (atomic-free aggregate) ----------------
// one wave per dst node; lane owns 2 adjacent columns.
__global__ __launch_bounds__(256) void gather_mid(
        const unsigned* __restrict__ sorted, const int* __restrict__ base,
        const int* __restrict__ cnt, const ushort* __restrict__ xw,
        float* __restrict__ mid, int rel0) {
    const int w = threadIdx.x >> 6, lane = threadIdx.x & 63;
    const int n = blockIdx.x * 4 + w;
    if (n >= N_NODES) return;
    const int b = base[n], c = cnt[n];
    float a0 = 0.f, a1 = 0.f;
    int matched = 0;
#pragma unroll 4
    for (int i = 0; i < c; ++i) {
        unsigned ds = sorted[b + i];
        int r = (int)(ds & 7u) - rel0;
        if ((unsigned)r >= 4u) continue;
        unsigned s = ds >> 3;
        unsigned v = *(const unsigned*)(xw + ((size_t)r * N_NODES + s) * 128 + lane * 2);
        a0 += b2f((ushort)(v & 0xffffu));
        a1 += b2f((ushort)(v >> 16));
        ++matched;
    }
    if (matched) {
        float* p = mid + (size_t)n * 128 + lane * 2;
        p[0] += a0; p[1] += a1;
    }
}

// ---------------- launch ----------------

extern "C" void kernel_launch(void* const* d_in, const int* in_sizes, int n_in,
                              void* d_out, int out_size, void* d_ws, size_t ws_size,
                              hipStream_t stream) {
    const float* x     = (const float*)d_in[0];
    const int*   src   = (const int*)  d_in[1];
    const int*   dst   = (const int*)  d_in[2];
    const int*   etype = (const int*)  d_in[3];
    const float* Wrel  = (const float*)d_in[4];
    const float* Wloop = (const float*)d_in[5];
    const float* brel  = (const float*)d_in[6];
    const float* W1    = (const float*)d_in[7];
    const float* b1    = (const float*)d_in[8];
    const float* W2    = (const float*)d_in[9];
    const float* b2    = (const float*)d_in[10];
    float* out = (float*)d_out;

    // ws layout — total 54,896,384 B (round-2 proved >= 64,491,520 B is available)
    char* ws = (char*)d_ws;
    ushort* xw  = (ushort*)ws;                     // 51,200,000 B  4-rel bf16 slices; reused as h [50000][256] bf16
    ushort* wt  = (ushort*)(ws + 51200000);        //    491,520 B  weights bf16 transposed
    char* meta  = ws + 51691520;
    int* cnt    = (int*)(meta);                    // 200,704 B
    int* base   = (int*)(meta + 200704);           // 200,704 B
    int* cursor = (int*)(meta + 401408);           // 200,704 B
    int* tincl  = (int*)(meta + 602112);           // 200,704 B
    int* bsum   = (int*)(meta + 802816);           //   1,024 B
    int* bex    = (int*)(meta + 803840);           //   1,024 B
    unsigned* sorted = (unsigned*)(meta + 804864); // 2,400,000 B  (meta end = 54,896,384)

    const ushort* wtl = wt;              // [128][128]
    const ushort* wtr = wt + 16384;      // [8][128][128]
    const ushort* w1t = wt + 147456;     // [256][256]
    const ushort* w2t = wt + 212992;     // [128][256]

    transpose_wts<<<dim3(64, 11), 256, 0, stream>>>(Wloop, Wrel, W1, W2, wt);

    // CSR build (counting sort of edges by dst)
    zero_cnt<<<N_TILES, 256, 0, stream>>>(cnt);
    hist_dst<<<(N_EDGES + 255) / 256, 256, 0, stream>>>(dst, cnt);
    scan_tiles<<<N_TILES, 256, 0, stream>>>(cnt, tincl, bsum);
    scan_bsum<<<1, 256, 0, stream>>>(bsum, bex);
    finalize_base<<<N_TILES, 256, 0, stream>>>(cnt, tincl, bex, base, cursor);
    scatter_ids<<<(N_EDGES + 255) / 256, 256, 0, stream>>>(src, dst, etype, cursor, sorted);

    // mid (= d_out, f32) = x @ Wloop + brel
    mfma_gemm<128, 128, 0, 0><<<dim3(782, 1), 256, 0, stream>>>(x, nullptr, wtl, brel, out);

    for (int g = 0; g < 2; ++g) {
        // xw[b] = x @ Wrel[g*4+b]  (bf16), b = 0..3
        mfma_gemm<128, 128, 0, 1><<<dim3(782, 4), 256, 0, stream>>>(
            x, nullptr, wtr + (size_t)g * 4 * 16384, nullptr, (void*)xw);
        // mid[dst] += xw[etype-g*4][src]  (atomic-free, CSR)
        gather_mid<<<(N_NODES + 3) / 4, 256, 0, stream>>>(sorted, base, cnt, xw, out, g * 4);
    }

    // h (bf16, in xw region) = relu(concat(x, mid) @ W1 + b1)
    mfma_gemm<256, 256, 1, 2><<<dim3(782, 1), 256, 0, stream>>>(x, out, w1t, b1, (void*)xw);
    // out = h @ W2 + b2
    mfma_gemm<256, 128, 2, 0><<<dim3(782, 1), 256, 0, stream>>>((void*)xw, nullptr, w2t, b2, out);
}

// Round 6
// 304.975 us; speedup vs baseline: 2.9385x; 1.5102x over previous
//
#include <hip/hip_runtime.h>

#define N_NODES 50000
#define N_EDGES 600000
#define N_REL 8
#define NT_PAD 50176      // 196 * 256
#define N_TILES 196

typedef __attribute__((ext_vector_type(8))) short bf16x8;
typedef __attribute__((ext_vector_type(4))) float f32x4;

__device__ __forceinline__ ushort f2b(float f) {
    union { float f; unsigned u; } v; v.f = f;
    unsigned r = v.u + 0x7FFFu + ((v.u >> 16) & 1u);
    return (ushort)(r >> 16);
}
__device__ __forceinline__ float b2f(ushort s) {
    union { unsigned u; float f; } v; v.u = ((unsigned)s) << 16;
    return v.f;
}

// ---------------- weight transpose+convert ----------------

__global__ void transpose_wts(const float* __restrict__ Wloop, const float* __restrict__ Wrel,
                              const float* __restrict__ W1, const float* __restrict__ W2,
                              ushort* __restrict__ wt) {
    int y = blockIdx.y;
    const float* src; int K, C; size_t doff;
    if (y == 0)      { src = Wloop;                       K = 128; C = 128; doff = 0; }
    else if (y <= 8) { src = Wrel + (size_t)(y - 1) * 16384; K = 128; C = 128; doff = 16384 + (size_t)(y - 1) * 16384; }
    else if (y == 9) { src = W1;                          K = 256; C = 256; doff = 147456; }
    else             { src = W2;                          K = 256; C = 128; doff = 212992; }
    int total = K * C;
    for (int idx = blockIdx.x * 256 + threadIdx.x; idx < total; idx += gridDim.x * 256) {
        int c = idx / K, k = idx - c * K;
        wt[doff + idx] = f2b(src[k * C + c]);
    }
}

// ---------------- MFMA GEMM, LDS-staged B ----------------
// out[r][c] = sum_k A[r][k] * Bt[c][k], 128 cols per block (col chunk or relation
// selected by blockIdx.y: Btb = Bt + y*128*K covers both).
// Per 128-k phase: stage B panel [128 cols][128 k] bf16 into LDS (row stride 136
// shorts), then 4x8 MFMA with A streamed from global.
// AMODE 0: A = f32 [N][128] (K=128), inline convert.
// AMODE 1: K=256: phase 0 reads Av (f32 [N][128]), phase 1 reads Amid (f32 [N][128]).
// AMODE 2: A = bf16 [N][K].
// OMODE 0: f32 out + bias. OMODE 1: bf16 out, no bias, slice y (out + y*N*128).
// OMODE 2: bf16 relu(out+bias), CTOT-wide rows.
template<int K, int CTOT, int AMODE, int OMODE>
__global__ __launch_bounds__(256) void mfma_gemm(
        const void* __restrict__ Av, const float* __restrict__ Amid,
        const ushort* __restrict__ Bt, const float* __restrict__ bias,
        void* __restrict__ outv) {
    __shared__ ushort bs[128 * 136];
    const int t = threadIdx.x;
    const int wave = t >> 6, lane = t & 63;
    const int lr = lane & 15, lg = lane >> 4;
    const int row0 = blockIdx.x * 64 + wave * 16;
    const ushort* Btb = Bt + (size_t)blockIdx.y * 128 * K;

    int arow = row0 + lr;
    if (arow >= N_NODES) arow = 0;

    f32x4 acc[8];
#pragma unroll
    for (int nt = 0; nt < 8; ++nt) acc[nt] = (f32x4){0.f, 0.f, 0.f, 0.f};

#pragma unroll
    for (int kp = 0; kp < K / 128; ++kp) {
        // A fragments for this 128-k phase (global, issued before staging)
        bf16x8 af[4];
#pragma unroll
        for (int kc = 0; kc < 4; ++kc) {
            if (AMODE == 2) {
                af[kc] = *(const bf16x8*)((const ushort*)Av + (size_t)arow * K + kp * 128 + kc * 32 + lg * 8);
            } else {
                const float* fp = (AMODE == 0 || kp == 0)
                    ? (const float*)Av + (size_t)arow * 128 + kc * 32 + lg * 8
                    : Amid + (size_t)arow * 128 + kc * 32 + lg * 8;
                f32x4 m0 = *(const f32x4*)fp;
                f32x4 m1 = *(const f32x4*)(fp + 4);
                union { bf16x8 v; ushort s[8]; } u;
                u.s[0] = f2b(m0[0]); u.s[1] = f2b(m0[1]); u.s[2] = f2b(m0[2]); u.s[3] = f2b(m0[3]);
                u.s[4] = f2b(m1[0]); u.s[5] = f2b(m1[1]); u.s[6] = f2b(m1[2]); u.s[7] = f2b(m1[3]);
                af[kc] = u.v;
            }
        }
        if (kp) __syncthreads();   // prev phase's LDS reads must finish before overwrite
        // stage B panel: 2048 granules of 16B; col c = idx>>4 (0..127), granule gk = idx&15 (0..15)
#pragma unroll
        for (int it = 0; it < 8; ++it) {
            int idx = t + it * 256;          // granule 0..2047
            int c = idx >> 4, gk = idx & 15;
            *(bf16x8*)(bs + c * 136 + gk * 8) =
                *(const bf16x8*)(Btb + (size_t)c * K + kp * 128 + gk * 8);
        }
        __syncthreads();
#pragma unroll
        for (int kc = 0; kc < 4; ++kc) {
#pragma unroll
            for (int nt = 0; nt < 8; ++nt) {
                bf16x8 bf = *(const bf16x8*)(bs + (nt * 16 + lr) * 136 + kc * 32 + lg * 8);
                acc[nt] = __builtin_amdgcn_mfma_f32_16x16x32_bf16(af[kc], bf, acc[nt], 0, 0, 0);
            }
        }
    }

    const int colbase = (OMODE == 1) ? 0 : blockIdx.y * 128;
#pragma unroll
    for (int nt = 0; nt < 8; ++nt) {
        const int col = nt * 16 + lr;
        float bv = (OMODE == 1) ? 0.f : bias[colbase + col];
#pragma unroll
        for (int j = 0; j < 4; ++j) {
            const int r = row0 + lg * 4 + j;
            if (r >= N_NODES) continue;
            float vv = acc[nt][j];
            if (OMODE == 0) {
                ((float*)outv)[(size_t)r * CTOT + colbase + col] = vv + bv;
            } else if (OMODE == 1) {
                ((ushort*)outv)[((size_t)blockIdx.y * N_NODES + r) * 128 + col] = f2b(vv);
            } else {
                ((ushort*)outv)[(size_t)r * CTOT + colbase + col] = f2b(fmaxf(vv + bv, 0.f));
            }
        }
    }
}

// ---------------- CSR build (counting sort by dst) ----------------

__global__ void zero_cnt(int* __restrict__ cnt) {
    int i = blockIdx.x * 256 + threadIdx.x;
    if (i < NT_PAD) cnt[i] = 0;
}

__global__ void hist_dst(const int* __restrict__ dst, int* __restrict__ cnt) {
    int e = blockIdx.x * 256 + threadIdx.x;
    if (e < N_EDGES) atomicAdd(&cnt[dst[e]], 1);
}

__global__ void scan_tiles(const int* __restrict__ cnt, int* __restrict__ tincl, int* __restrict__ bsum) {
    __shared__ int s[256];
    int i = blockIdx.x * 256 + threadIdx.x;
    int v = cnt[i];
    s[threadIdx.x] = v;
    __syncthreads();
    for (int off = 1; off < 256; off <<= 1) {
        int add = (threadIdx.x >= off) ? s[threadIdx.x - off] : 0;
        __syncthreads();
        s[threadIdx.x] += add;
        __syncthreads();
    }
    tincl[i] = s[threadIdx.x];
    if (threadIdx.x == 255) bsum[blockIdx.x] = s[255];
}

__global__ void scan_bsum(const int* __restrict__ bsum, int* __restrict__ bex) {
    __shared__ int s[256];
    int v = (threadIdx.x < N_TILES) ? bsum[threadIdx.x] : 0;
    s[threadIdx.x] = v;
    __syncthreads();
    for (int off = 1; off < 256; off <<= 1) {
        int add = (threadIdx.x >= off) ? s[threadIdx.x - off] : 0;
        __syncthreads();
        s[threadIdx.x] += add;
        __syncthreads();
    }
    if (threadIdx.x < N_TILES) bex[threadIdx.x] = s[threadIdx.x] - v;
}

__global__ void finalize_base(const int* __restrict__ cnt, const int* __restrict__ tincl,
                              const int* __restrict__ bex, int* __restrict__ base,
                              int* __restrict__ cursor) {
    int i = blockIdx.x * 256 + threadIdx.x;
    int b = tincl[i] - cnt[i] + bex[blockIdx.x];
    base[i] = b; cursor[i] = b;
}

__global__ void scatter_ids(const int* __restrict__ src, const int* __restrict__ dst,
                            const int* __restrict__ et, int* __restrict__ cursor,
                            unsigned* __restrict__ sorted) {
    int e = blockIdx.x * 256 + threadIdx.x;
    if (e >= N_EDGES) return;
    int pos = atomicAdd(&cursor[dst[e]], 1);
    sorted[pos] = ((unsigned)src[e] << 3) | (unsigned)et[e];
}

// ---------------- gather (atomic-free aggregate) ----------------

__global__ __launch_bounds__(256) void gather_mid(
        const unsigned* __restrict__ sorted, const int* __restrict__ base,
        const int* __restrict__ cnt, const ushort* __restrict__ xw,
        float* __restrict__ mid, int rel0) {
    const int w = threadIdx.x >> 6, lane = threadIdx.x & 63;
    const int n = blockIdx.x * 4 + w;
    if (n >= N_NODES) return;
    const int b = base[n], c = cnt[n];
    float a0 = 0.f, a1 = 0.f;
    int matched = 0;
#pragma unroll 4
    for (int i = 0; i < c; ++i) {
        unsigned ds = sorted[b + i];
        int r = (int)(ds & 7u) - rel0;
        if ((unsigned)r >= 4u) continue;
        unsigned s = ds >> 3;
        unsigned v = *(const unsigned*)(xw + ((size_t)r * N_NODES + s) * 128 + lane * 2);
        a0 += b2f((ushort)(v & 0xffffu));
        a1 += b2f((ushort)(v >> 16));
        ++matched;
    }
    if (matched) {
        float* p = mid + (size_t)n * 128 + lane * 2;
        p[0] += a0; p[1] += a1;
    }
}

// ---------------- launch ----------------

extern "C" void kernel_launch(void* const* d_in, const int* in_sizes, int n_in,
                              void* d_out, int out_size, void* d_ws, size_t ws_size,
                              hipStream_t stream) {
    const float* x     = (const float*)d_in[0];
    const int*   src   = (const int*)  d_in[1];
    const int*   dst   = (const int*)  d_in[2];
    const int*   etype = (const int*)  d_in[3];
    const float* Wrel  = (const float*)d_in[4];
    const float* Wloop = (const float*)d_in[5];
    const float* brel  = (const float*)d_in[6];
    const float* W1    = (const float*)d_in[7];
    const float* b1    = (const float*)d_in[8];
    const float* W2    = (const float*)d_in[9];
    const float* b2    = (const float*)d_in[10];
    float* out = (float*)d_out;

    // ws layout — total 54,896,384 B (round-4 proven envelope)
    char* ws = (char*)d_ws;
    ushort* xw  = (ushort*)ws;                     // 51,200,000 B  4-rel bf16 slices; reused as h [50000][256] bf16
    ushort* wt  = (ushort*)(ws + 51200000);        //    491,520 B  weights bf16 transposed
    char* meta  = ws + 51691520;
    int* cnt    = (int*)(meta);                    // 200,704 B
    int* base   = (int*)(meta + 200704);           // 200,704 B
    int* cursor = (int*)(meta + 401408);           // 200,704 B
    int* tincl  = (int*)(meta + 602112);           // 200,704 B
    int* bsum   = (int*)(meta + 802816);           //   1,024 B
    int* bex    = (int*)(meta + 803840);           //   1,024 B
    unsigned* sorted = (unsigned*)(meta + 804864); // 2,400,000 B  (meta end = 54,896,384)

    const ushort* wtl = wt;              // [128][128]
    const ushort* wtr = wt + 16384;      // [8][128][128]
    const ushort* w1t = wt + 147456;     // [256][256]
    const ushort* w2t = wt + 212992;     // [128][256]

    transpose_wts<<<dim3(64, 11), 256, 0, stream>>>(Wloop, Wrel, W1, W2, wt);

    // CSR build (counting sort of edges by dst)
    zero_cnt<<<N_TILES, 256, 0, stream>>>(cnt);
    hist_dst<<<(N_EDGES + 255) / 256, 256, 0, stream>>>(dst, cnt);
    scan_tiles<<<N_TILES, 256, 0, stream>>>(cnt, tincl, bsum);
    scan_bsum<<<1, 256, 0, stream>>>(bsum, bex);
    finalize_base<<<N_TILES, 256, 0, stream>>>(cnt, tincl, bex, base, cursor);
    scatter_ids<<<(N_EDGES + 255) / 256, 256, 0, stream>>>(src, dst, etype, cursor, sorted);

    // mid (= d_out, f32) = x @ Wloop + brel
    mfma_gemm<128, 128, 0, 0><<<dim3(782, 1), 256, 0, stream>>>(x, nullptr, wtl, brel, out);

    for (int g = 0; g < 2; ++g) {
        // xw[b] = x @ Wrel[g*4+b]  (bf16), b = 0..3
        mfma_gemm<128, 128, 0, 1><<<dim3(782, 4), 256, 0, stream>>>(
            x, nullptr, wtr + (size_t)g * 4 * 16384, nullptr, (void*)xw);
        // mid[dst] += xw[etype-g*4][src]  (atomic-free, CSR)
        gather_mid<<<(N_NODES + 3) / 4, 256, 0, stream>>>(sorted, base, cnt, xw, out, g * 4);
    }

    // h (bf16, in xw region) = relu(concat(x, mid) @ W1 + b1), col chunks via grid.y
    mfma_gemm<256, 256, 1, 2><<<dim3(782, 2), 256, 0, stream>>>(x, out, w1t, b1, (void*)xw);
    // out = h @ W2 + b2
    mfma_gemm<256, 128, 2, 0><<<dim3(782, 1), 256, 0, stream>>>((void*)xw, nullptr, w2t, b2, out);
}

// Round 7
// 252.687 us; speedup vs baseline: 3.5466x; 1.2069x over previous
//
#include <hip/hip_runtime.h>

#define N_NODES 50000
#define N_EDGES 600000
#define N_REL 8
#define NKEY 100000            // dst*2 + group
#define NKEY_PAD 100352        // 392 * 256
#define N_TILES2 392

typedef __attribute__((ext_vector_type(8))) short bf16x8;
typedef __attribute__((ext_vector_type(4))) float f32x4;

__device__ __forceinline__ ushort f2b(float f) {
    union { float f; unsigned u; } v; v.f = f;
    unsigned r = v.u + 0x7FFFu + ((v.u >> 16) & 1u);
    return (ushort)(r >> 16);
}
__device__ __forceinline__ float b2f(ushort s) {
    union { unsigned u; float f; } v; v.u = ((unsigned)s) << 16;
    return v.f;
}

// ---------------- weight transpose+convert ----------------

__global__ void transpose_wts(const float* __restrict__ Wloop, const float* __restrict__ Wrel,
                              const float* __restrict__ W1, const float* __restrict__ W2,
                              ushort* __restrict__ wt) {
    int y = blockIdx.y;
    const float* src; int K, C; size_t doff;
    if (y == 0)      { src = Wloop;                       K = 128; C = 128; doff = 0; }
    else if (y <= 8) { src = Wrel + (size_t)(y - 1) * 16384; K = 128; C = 128; doff = 16384 + (size_t)(y - 1) * 16384; }
    else if (y == 9) { src = W1;                          K = 256; C = 256; doff = 147456; }
    else             { src = W2;                          K = 256; C = 128; doff = 212992; }
    int total = K * C;
    for (int idx = blockIdx.x * 256 + threadIdx.x; idx < total; idx += gridDim.x * 256) {
        int c = idx / K, k = idx - c * K;
        wt[doff + idx] = f2b(src[k * C + c]);
    }
}

// ---------------- MFMA GEMM, LDS-staged B (unchanged from round 6) ----------------
template<int K, int CTOT, int AMODE, int OMODE>
__global__ __launch_bounds__(256) void mfma_gemm(
        const void* __restrict__ Av, const float* __restrict__ Amid,
        const ushort* __restrict__ Bt, const float* __restrict__ bias,
        void* __restrict__ outv) {
    __shared__ ushort bs[128 * 136];
    const int t = threadIdx.x;
    const int wave = t >> 6, lane = t & 63;
    const int lr = lane & 15, lg = lane >> 4;
    const int row0 = blockIdx.x * 64 + wave * 16;
    const ushort* Btb = Bt + (size_t)blockIdx.y * 128 * K;

    int arow = row0 + lr;
    if (arow >= N_NODES) arow = 0;

    f32x4 acc[8];
#pragma unroll
    for (int nt = 0; nt < 8; ++nt) acc[nt] = (f32x4){0.f, 0.f, 0.f, 0.f};

#pragma unroll
    for (int kp = 0; kp < K / 128; ++kp) {
        bf16x8 af[4];
#pragma unroll
        for (int kc = 0; kc < 4; ++kc) {
            if (AMODE == 2) {
                af[kc] = *(const bf16x8*)((const ushort*)Av + (size_t)arow * K + kp * 128 + kc * 32 + lg * 8);
            } else {
                const float* fp = (AMODE == 0 || kp == 0)
                    ? (const float*)Av + (size_t)arow * 128 + kc * 32 + lg * 8
                    : Amid + (size_t)arow * 128 + kc * 32 + lg * 8;
                f32x4 m0 = *(const f32x4*)fp;
                f32x4 m1 = *(const f32x4*)(fp + 4);
                union { bf16x8 v; ushort s[8]; } u;
                u.s[0] = f2b(m0[0]); u.s[1] = f2b(m0[1]); u.s[2] = f2b(m0[2]); u.s[3] = f2b(m0[3]);
                u.s[4] = f2b(m1[0]); u.s[5] = f2b(m1[1]); u.s[6] = f2b(m1[2]); u.s[7] = f2b(m1[3]);
                af[kc] = u.v;
            }
        }
        if (kp) __syncthreads();
#pragma unroll
        for (int it = 0; it < 8; ++it) {
            int idx = t + it * 256;          // granule 0..2047
            int c = idx >> 4, gk = idx & 15;
            *(bf16x8*)(bs + c * 136 + gk * 8) =
                *(const bf16x8*)(Btb + (size_t)c * K + kp * 128 + gk * 8);
        }
        __syncthreads();
#pragma unroll
        for (int kc = 0; kc < 4; ++kc) {
#pragma unroll
            for (int nt = 0; nt < 8; ++nt) {
                bf16x8 bf = *(const bf16x8*)(bs + (nt * 16 + lr) * 136 + kc * 32 + lg * 8);
                acc[nt] = __builtin_amdgcn_mfma_f32_16x16x32_bf16(af[kc], bf, acc[nt], 0, 0, 0);
            }
        }
    }

    const int colbase = (OMODE == 1) ? 0 : blockIdx.y * 128;
#pragma unroll
    for (int nt = 0; nt < 8; ++nt) {
        const int col = nt * 16 + lr;
        float bv = (OMODE == 1) ? 0.f : bias[colbase + col];
#pragma unroll
        for (int j = 0; j < 4; ++j) {
            const int r = row0 + lg * 4 + j;
            if (r >= N_NODES) continue;
            float vv = acc[nt][j];
            if (OMODE == 0) {
                ((float*)outv)[(size_t)r * CTOT + colbase + col] = vv + bv;
            } else if (OMODE == 1) {
                ((ushort*)outv)[((size_t)blockIdx.y * N_NODES + r) * 128 + col] = f2b(vv);
            } else {
                ((ushort*)outv)[(size_t)r * CTOT + colbase + col] = f2b(fmaxf(vv + bv, 0.f));
            }
        }
    }
}

// ---------------- CSR build, keyed by dst*2 + (etype>=4) ----------------

__global__ void zero_cnt(int* __restrict__ cnt) {
    int i = blockIdx.x * 256 + threadIdx.x;
    if (i < NKEY_PAD) cnt[i] = 0;
}

__global__ void hist_key(const int* __restrict__ dst, const int* __restrict__ et,
                         int* __restrict__ cnt) {
    int e = blockIdx.x * 256 + threadIdx.x;
    if (e < N_EDGES) atomicAdd(&cnt[dst[e] * 2 + (et[e] >> 2)], 1);
}

__global__ void scan_tiles(const int* __restrict__ cnt, int* __restrict__ tincl, int* __restrict__ bsum) {
    __shared__ int s[256];
    int i = blockIdx.x * 256 + threadIdx.x;
    int v = cnt[i];
    s[threadIdx.x] = v;
    __syncthreads();
    for (int off = 1; off < 256; off <<= 1) {
        int add = (threadIdx.x >= off) ? s[threadIdx.x - off] : 0;
        __syncthreads();
        s[threadIdx.x] += add;
        __syncthreads();
    }
    tincl[i] = s[threadIdx.x];
    if (threadIdx.x == 255) bsum[blockIdx.x] = s[255];
}

// exclusive scan of the 392 tile sums (1 block x 512)
__global__ void scan_bsum(const int* __restrict__ bsum, int* __restrict__ bex) {
    __shared__ int s[512];
    int v = (threadIdx.x < N_TILES2) ? bsum[threadIdx.x] : 0;
    s[threadIdx.x] = v;
    __syncthreads();
    for (int off = 1; off < 512; off <<= 1) {
        int add = (threadIdx.x >= off) ? s[threadIdx.x - off] : 0;
        __syncthreads();
        s[threadIdx.x] += add;
        __syncthreads();
    }
    if (threadIdx.x < N_TILES2) bex[threadIdx.x] = s[threadIdx.x] - v;
}

__global__ void finalize_base(const int* __restrict__ cnt, const int* __restrict__ tincl,
                              const int* __restrict__ bex, int* __restrict__ base,
                              int* __restrict__ cursor) {
    int i = blockIdx.x * 256 + threadIdx.x;
    int b = tincl[i] - cnt[i] + bex[blockIdx.x];
    base[i] = b; cursor[i] = b;
}

__global__ void scatter_ids(const int* __restrict__ src, const int* __restrict__ dst,
                            const int* __restrict__ et, int* __restrict__ cursor,
                            unsigned* __restrict__ sorted) {
    int e = blockIdx.x * 256 + threadIdx.x;
    if (e >= N_EDGES) return;
    int pos = atomicAdd(&cursor[dst[e] * 2 + (et[e] >> 2)], 1);
    sorted[pos] = ((unsigned)src[e] << 2) | (unsigned)(et[e] & 3);
}

// ---------------- gather (atomic-free, group-split CSR, 4-way pipelined) ----------------

__device__ __forceinline__ unsigned ldrow(const ushort* __restrict__ xw, unsigned ds, int lane) {
    return *(const unsigned*)(xw + ((size_t)(ds & 3u) * N_NODES + (ds >> 2)) * 128 + lane * 2);
}

__global__ __launch_bounds__(256) void gather_mid(
        const unsigned* __restrict__ sorted, const int* __restrict__ base2,
        const int* __restrict__ cnt2, const ushort* __restrict__ xw,
        float* __restrict__ mid, int g) {
    const int w = threadIdx.x >> 6, lane = threadIdx.x & 63;
    const int n = blockIdx.x * 4 + w;
    if (n >= N_NODES) return;
    const int key = n * 2 + g;
    const int b = base2[key], c = cnt2[key];
    if (c == 0) return;

    float a0 = 0.f, a1 = 0.f, b0 = 0.f, b1 = 0.f;
    float c0 = 0.f, c1 = 0.f, d0 = 0.f, d1 = 0.f;
    const unsigned* sp = sorted + b;
    int i = 0;
    for (; i + 4 <= c; i += 4) {
        unsigned s0 = sp[i], s1 = sp[i + 1], s2 = sp[i + 2], s3 = sp[i + 3];
        unsigned v0 = ldrow(xw, s0, lane);
        unsigned v1 = ldrow(xw, s1, lane);
        unsigned v2 = ldrow(xw, s2, lane);
        unsigned v3 = ldrow(xw, s3, lane);
        a0 += b2f((ushort)(v0 & 0xffffu)); a1 += b2f((ushort)(v0 >> 16));
        b0 += b2f((ushort)(v1 & 0xffffu)); b1 += b2f((ushort)(v1 >> 16));
        c0 += b2f((ushort)(v2 & 0xffffu)); c1 += b2f((ushort)(v2 >> 16));
        d0 += b2f((ushort)(v3 & 0xffffu)); d1 += b2f((ushort)(v3 >> 16));
    }
    for (; i < c; ++i) {
        unsigned v = ldrow(xw, sp[i], lane);
        a0 += b2f((ushort)(v & 0xffffu)); a1 += b2f((ushort)(v >> 16));
    }
    float r0 = (a0 + b0) + (c0 + d0);
    float r1 = (a1 + b1) + (c1 + d1);
    float2* p = (float2*)(mid + (size_t)n * 128) + lane;
    float2 old = *p;
    old.x += r0; old.y += r1;
    *p = old;
}

// ---------------- launch ----------------

extern "C" void kernel_launch(void* const* d_in, const int* in_sizes, int n_in,
                              void* d_out, int out_size, void* d_ws, size_t ws_size,
                              hipStream_t stream) {
    const float* x     = (const float*)d_in[0];
    const int*   src   = (const int*)  d_in[1];
    const int*   dst   = (const int*)  d_in[2];
    const int*   etype = (const int*)  d_in[3];
    const float* Wrel  = (const float*)d_in[4];
    const float* Wloop = (const float*)d_in[5];
    const float* brel  = (const float*)d_in[6];
    const float* W1    = (const float*)d_in[7];
    const float* b1    = (const float*)d_in[8];
    const float* W2    = (const float*)d_in[9];
    const float* b2    = (const float*)d_in[10];
    float* out = (float*)d_out;

    // ws layout — total 55,701,248 B (< 64,491,520 proven envelope)
    char* ws = (char*)d_ws;
    ushort* xw  = (ushort*)ws;                     // 51,200,000 B  4-rel bf16 slices; reused as h [50000][256] bf16
    ushort* wt  = (ushort*)(ws + 51200000);        //    491,520 B  weights bf16 transposed
    char* meta   = ws + 51691520;
    int* cnt2    = (int*)(meta);                   // 401,408 B
    int* base2   = (int*)(meta + 401408);          // 401,408 B
    int* cursor2 = (int*)(meta + 802816);          // 401,408 B
    int* tincl2  = (int*)(meta + 1204224);         // 401,408 B
    int* bsum    = (int*)(meta + 1605632);         //   2,048 B
    int* bex     = (int*)(meta + 1607680);         //   2,048 B
    unsigned* sorted = (unsigned*)(meta + 1609728);// 2,400,000 B  (end = 55,701,248)

    const ushort* wtl = wt;              // [128][128]
    const ushort* wtr = wt + 16384;      // [8][128][128]
    const ushort* w1t = wt + 147456;     // [256][256]
    const ushort* w2t = wt + 212992;     // [128][256]

    transpose_wts<<<dim3(64, 11), 256, 0, stream>>>(Wloop, Wrel, W1, W2, wt);

    // CSR build, keyed by dst*2 + (etype>=4)
    zero_cnt<<<N_TILES2, 256, 0, stream>>>(cnt2);
    hist_key<<<(N_EDGES + 255) / 256, 256, 0, stream>>>(dst, etype, cnt2);
    scan_tiles<<<N_TILES2, 256, 0, stream>>>(cnt2, tincl2, bsum);
    scan_bsum<<<1, 512, 0, stream>>>(bsum, bex);
    finalize_base<<<N_TILES2, 256, 0, stream>>>(cnt2, tincl2, bex, base2, cursor2);
    scatter_ids<<<(N_EDGES + 255) / 256, 256, 0, stream>>>(src, dst, etype, cursor2, sorted);

    // mid (= d_out, f32) = x @ Wloop + brel
    mfma_gemm<128, 128, 0, 0><<<dim3(782, 1), 256, 0, stream>>>(x, nullptr, wtl, brel, out);

    for (int g = 0; g < 2; ++g) {
        // xw[b] = x @ Wrel[g*4+b]  (bf16), b = 0..3
        mfma_gemm<128, 128, 0, 1><<<dim3(782, 4), 256, 0, stream>>>(
            x, nullptr, wtr + (size_t)g * 4 * 16384, nullptr, (void*)xw);
        // mid[dst] += xw[rel_local][src]  (atomic-free, group-split CSR)
        gather_mid<<<(N_NODES + 3) / 4, 256, 0, stream>>>(sorted, base2, cnt2, xw, out, g);
    }

    // h (bf16, in xw region) = relu(concat(x, mid) @ W1 + b1), col chunks via grid.y
    mfma_gemm<256, 256, 1, 2><<<dim3(782, 2), 256, 0, stream>>>(x, out, w1t, b1, (void*)xw);
    // out = h @ W2 + b2
    mfma_gemm<256, 128, 2, 0><<<dim3(782, 1), 256, 0, stream>>>((void*)xw, nullptr, w2t, b2, out);
}